// Round 1
// baseline (389.496 us; speedup 1.0000x reference)
//
#include <hip/hip_runtime.h>
#include <hip/hip_bf16.h>
#include <cstdint>

// Problem constants
#define BB   256
#define TT   128
#define DD   300
#define HH   16
#define GG   64      // 4*H
#define CC   5
#define ROWS (BB*TT) // 32768

// ---------------------------------------------------------------------------
// Kernel 1: xg[row, g] = sum_d emb[x[row], d] * W_ih[g, d] + b_ih[g] + b_hh[g]
// Tile: 128 rows x 64 cols per block, 256 threads, per-thread 8 rows x 4 cols.
// W_ih staged transposed in LDS in K-chunks of 100 (fits 64KB static LDS cap).
// ---------------------------------------------------------------------------
__global__ __launch_bounds__(256) void xg_gemm_kernel(
    const int* __restrict__ x, const float* __restrict__ emb,
    const float* __restrict__ W_ih, const float* __restrict__ b_ih,
    const float* __restrict__ b_hh, float* __restrict__ xg) {

  __shared__ float Ws[100][68];  // [d_local][col], pad 68 keeps 16B align + no conflicts

  const int t  = threadIdx.x;
  const int tx = t & 15;   // col quad: cols 4*tx .. 4*tx+3
  const int ty = t >> 4;   // row octet: rows row0 .. row0+7
  const int row0 = blockIdx.x * 128 + ty * 8;

  // Gather row base pointers (emb rows are 1200B = 16B-aligned)
  const float* arow[8];
#pragma unroll
  for (int i = 0; i < 8; i++)
    arow[i] = emb + (size_t)x[row0 + i] * DD;

  float acc[8][4] = {};

  for (int ch = 0; ch < 3; ch++) {
    const int dbase = ch * 100;
    __syncthreads();
    // Stage W_ih chunk transposed: Ws[d][c] = W_ih[c*300 + dbase + d]
    for (int idx = t; idx < 64 * 100; idx += 256) {
      int c = idx / 100;
      int d = idx - c * 100;
      Ws[d][c] = W_ih[c * DD + dbase + d];
    }
    __syncthreads();

    for (int q = 0; q < 25; q++) {
      const int d0 = dbase + q * 4;
      float4 wq[4];
      wq[0] = *(const float4*)&Ws[q * 4 + 0][tx * 4];
      wq[1] = *(const float4*)&Ws[q * 4 + 1][tx * 4];
      wq[2] = *(const float4*)&Ws[q * 4 + 2][tx * 4];
      wq[3] = *(const float4*)&Ws[q * 4 + 3][tx * 4];
      const float* wf = (const float*)wq;  // wf[j*4 + c] = W[col 4tx+c][d0+j]
#pragma unroll
      for (int i = 0; i < 8; i++) {
        float4 a = *(const float4*)(arow[i] + d0);
#pragma unroll
        for (int c = 0; c < 4; c++) {
          acc[i][c] = fmaf(a.x, wf[0 * 4 + c], acc[i][c]);
          acc[i][c] = fmaf(a.y, wf[1 * 4 + c], acc[i][c]);
          acc[i][c] = fmaf(a.z, wf[2 * 4 + c], acc[i][c]);
          acc[i][c] = fmaf(a.w, wf[3 * 4 + c], acc[i][c]);
        }
      }
    }
  }

  // Bias and store
  float bias[4];
#pragma unroll
  for (int c = 0; c < 4; c++)
    bias[c] = b_ih[tx * 4 + c] + b_hh[tx * 4 + c];

#pragma unroll
  for (int i = 0; i < 8; i++) {
    float4 o;
    o.x = acc[i][0] + bias[0];
    o.y = acc[i][1] + bias[1];
    o.z = acc[i][2] + bias[2];
    o.w = acc[i][3] + bias[3];
    *(float4*)&xg[(size_t)(row0 + i) * GG + tx * 4] = o;
  }
}

// ---------------------------------------------------------------------------
// Kernel 2: per-batch LSTM recurrence + output projection.
// One wave (64 lanes) per batch element; lane j owns gate element
// (gate = j>>4, k = j&15). h broadcast via readlane -> SGPRs.
// ---------------------------------------------------------------------------
__global__ __launch_bounds__(64) void lstm_seq_kernel(
    const float* __restrict__ xg, const float* __restrict__ W_hh,
    const float* __restrict__ W_out, const float* __restrict__ b_out,
    float* __restrict__ out) {

  __shared__ float xgs[TT * GG];   // 32 KB: this batch's gate preactivations
  __shared__ float hs[TT][HH];     // 8 KB: hidden states for output GEMM

  const int lane = threadIdx.x;
  const int b = blockIdx.x;
  const float* xgb = xg + (size_t)b * TT * GG;

  // Stage xg slab into LDS (coalesced float4)
#pragma unroll 4
  for (int i = 0; i < 32; i++) {
    int idx = (i * 64 + lane) * 4;
    *(float4*)&xgs[idx] = *(const float4*)&xgb[idx];
  }

  // W_hh row for this lane's gate element into registers
  float wh[16];
  {
    const float* wr = W_hh + lane * HH;
#pragma unroll
    for (int k = 0; k < 16; k++) wh[k] = wr[k];
  }
  __syncthreads();

  const int k = lane & 15;
  const int gate = lane >> 4;
  const float gscale = (gate == 2) ? -2.0f : -1.0f;  // tanh via 2*sigmoid(2x)-1
  const bool is_tanh = (gate == 2);

  float c = 0.0f;
  float hu[16];  // wave-uniform broadcast of h (lives in SGPRs)
#pragma unroll
  for (int kk = 0; kk < 16; kk++) hu[kk] = 0.0f;

  float g = xgs[lane];  // t = 0 prefetched
  for (int tstep = 0; tstep < TT; tstep++) {
    // Prefetch next step's preactivation (overlaps the dependent chain)
    int tn = (tstep + 1 < TT) ? (tstep + 1) : (TT - 1);
    float gnext = xgs[tn * GG + lane];

    // g += h . W_hh[j, :]
#pragma unroll
    for (int kk = 0; kk < 16; kk++) g = fmaf(hu[kk], wh[kk], g);

    // Branchless sigmoid/tanh: e = exp(gscale * g); s = 1/(1+e)
    float e = __expf(g * gscale);
    float s = __builtin_amdgcn_rcpf(1.0f + e);
    float act = is_tanh ? (2.0f * s - 1.0f) : s;

    // Gate exchange: lane gets i,f,g,o for its k
    float iv = __shfl(act, k);
    float fv = __shfl(act, k + 16);
    float gv = __shfl(act, k + 32);
    float ov = __shfl(act, k + 48);

    c = fmaf(fv, c, iv * gv);
    // tanh(c) = 2/(1+exp(-2c)) - 1  (saturates correctly at +-inf)
    float e2 = __expf(-2.0f * c);
    float tc = fmaf(2.0f, __builtin_amdgcn_rcpf(1.0f + e2), -1.0f);
    float hnew = ov * tc;

    if (lane < 16) hs[tstep][lane] = hnew;

    // Broadcast h to all lanes as wave-uniform scalars for next matvec
#pragma unroll
    for (int kk = 0; kk < 16; kk++)
      hu[kk] = __uint_as_float(__builtin_amdgcn_readlane(__float_as_uint(hnew), kk));

    g = gnext;
  }
  __syncthreads();

  // Output projection: out[b, t, cc] = hs[t] . W_out[cc, :] + b_out[cc]
  float* outb = out + (size_t)b * TT * CC;
  for (int idx = lane; idx < TT * CC; idx += 64) {
    int tt = idx / CC;
    int cc = idx - tt * CC;
    const float* wr = W_out + cc * HH;
    float accv = b_out[cc];
#pragma unroll
    for (int kk = 0; kk < 16; kk++) accv = fmaf(hs[tt][kk], wr[kk], accv);
    outb[idx] = accv;
  }
}

// ---------------------------------------------------------------------------
extern "C" void kernel_launch(void* const* d_in, const int* in_sizes, int n_in,
                              void* d_out, int out_size, void* d_ws, size_t ws_size,
                              hipStream_t stream) {
  const int*   x     = (const int*)d_in[0];
  const float* emb   = (const float*)d_in[1];
  const float* W_ih  = (const float*)d_in[2];
  const float* W_hh  = (const float*)d_in[3];
  const float* b_ih  = (const float*)d_in[4];
  const float* b_hh  = (const float*)d_in[5];
  const float* W_out = (const float*)d_in[6];
  const float* b_out = (const float*)d_in[7];
  float* out = (float*)d_out;
  float* xg  = (float*)d_ws;  // [32768][64] fp32 = 8.4 MB scratch

  xg_gemm_kernel<<<ROWS / 128, 256, 0, stream>>>(x, emb, W_ih, b_ih, b_hh, xg);
  lstm_seq_kernel<<<BB, 64, 0, stream>>>(xg, W_hh, W_out, b_out, out);
}

// Round 2
// 223.340 us; speedup vs baseline: 1.7440x; 1.7440x over previous
//
#include <hip/hip_runtime.h>
#include <hip/hip_bf16.h>
#include <cstdint>

// Problem constants
#define BB   256
#define TT   128
#define DD   300
#define HH   16
#define GG   64      // 4*H
#define CC   5
#define ROWS (BB*TT) // 32768

// ---------------------------------------------------------------------------
// Kernel 1: xg[row, g] = sum_d emb[x[row], d] * W_ih[g, d] + b_ih[g] + b_hh[g]
// 512 blocks x 256 threads. Tile: 64 rows x 64 cols. K chunked by 60 (5 chunks).
// A (gathered emb rows) staged in LDS with coalesced float4 loads.
// W_ih staged transposed in LDS. Per-thread 4x4 output tile.
// ---------------------------------------------------------------------------
__global__ __launch_bounds__(256) void xg_gemm_kernel(
    const int* __restrict__ x, const float* __restrict__ emb,
    const float* __restrict__ W_ih, const float* __restrict__ b_ih,
    const float* __restrict__ b_hh, float* __restrict__ xg) {

  __shared__ float As[64][60];   // 15.4 KB  [row][d_local]
  __shared__ float Ws[60][68];   // 16.3 KB  [d_local][col], padded to 68
  __shared__ int   xidx[64];

  const int t  = threadIdx.x;
  const int tx = t & 15;   // col quad: cols 4*tx .. 4*tx+3
  const int ty = t >> 4;   // row quad: rows 4*ty .. 4*ty+3
  const int row0 = blockIdx.x * 64;

  if (t < 64) xidx[t] = x[row0 + t];

  float acc[4][4] = {};

  for (int ch = 0; ch < 5; ch++) {
    const int dbase = ch * 60;
    __syncthreads();   // protects As/Ws reuse (and xidx on first pass)

    // Stage A: 64 rows x 15 float4 (coalesced within each emb row)
    for (int u = t; u < 960; u += 256) {
      int r = u / 15, f = u - r * 15;
      const float* src = emb + (size_t)xidx[r] * DD + dbase + f * 4;
      *(float4*)&As[r][f * 4] = *(const float4*)src;
    }
    // Stage W transposed: Ws[d][c] = W_ih[c*300 + dbase + d]
    for (int u = t; u < 960; u += 256) {
      int c = u / 15, f = u - c * 15;
      float4 w = *(const float4*)&W_ih[c * DD + dbase + f * 4];
      Ws[f * 4 + 0][c] = w.x;
      Ws[f * 4 + 1][c] = w.y;
      Ws[f * 4 + 2][c] = w.z;
      Ws[f * 4 + 3][c] = w.w;
    }
    __syncthreads();

    // Compute: 15 K-steps of 4
#pragma unroll
    for (int q = 0; q < 15; q++) {
      float4 wq[4];
      wq[0] = *(const float4*)&Ws[q * 4 + 0][tx * 4];
      wq[1] = *(const float4*)&Ws[q * 4 + 1][tx * 4];
      wq[2] = *(const float4*)&Ws[q * 4 + 2][tx * 4];
      wq[3] = *(const float4*)&Ws[q * 4 + 3][tx * 4];
      const float* wf = (const float*)wq;  // wf[j*4+c] = W[col 4tx+c][k=4q+j]
#pragma unroll
      for (int r = 0; r < 4; r++) {
        float4 a = *(const float4*)&As[ty * 4 + r][q * 4];
#pragma unroll
        for (int c = 0; c < 4; c++) {
          acc[r][c] = fmaf(a.x, wf[0 * 4 + c], acc[r][c]);
          acc[r][c] = fmaf(a.y, wf[1 * 4 + c], acc[r][c]);
          acc[r][c] = fmaf(a.z, wf[2 * 4 + c], acc[r][c]);
          acc[r][c] = fmaf(a.w, wf[3 * 4 + c], acc[r][c]);
        }
      }
    }
  }

  // Bias + store (coalesced: 16 lanes cover one 256B row segment)
  float bias[4];
#pragma unroll
  for (int c = 0; c < 4; c++)
    bias[c] = b_ih[tx * 4 + c] + b_hh[tx * 4 + c];

#pragma unroll
  for (int r = 0; r < 4; r++) {
    float4 o;
    o.x = acc[r][0] + bias[0];
    o.y = acc[r][1] + bias[1];
    o.z = acc[r][2] + bias[2];
    o.w = acc[r][3] + bias[3];
    *(float4*)&xg[(size_t)(row0 + ty * 4 + r) * GG + tx * 4] = o;
  }
}

// ---------------------------------------------------------------------------
// Kernel 2: per-batch LSTM recurrence + output projection.
// 256 blocks x 256 threads. All 4 waves stage the 32KB xg slab (deep ILP);
// wave 0 runs the serial recurrence; all waves do the output projection.
// ---------------------------------------------------------------------------
__global__ __launch_bounds__(256) void lstm_seq_kernel(
    const float* __restrict__ xg, const float* __restrict__ W_hh,
    const float* __restrict__ W_out, const float* __restrict__ b_out,
    float* __restrict__ out) {

  __shared__ float xgs[TT * GG];   // 32 KB
  __shared__ float hs[TT][HH];     // 8 KB

  const int t = threadIdx.x;
  const int b = blockIdx.x;

  // Cooperative slab staging: 8192 float4 / 256 threads = 32 each, fully
  // unrolled so many loads are in flight per thread.
  {
    const float4* __restrict__ src = (const float4*)(xg + (size_t)b * TT * GG);
    float4* dst = (float4*)xgs;
#pragma unroll
    for (int i = 0; i < 32; i++) {
      int idx = i * 256 + t;
      dst[idx] = src[idx];
    }
  }
  __syncthreads();

  if (t < 64) {
    const int lane = t;
    const int k = lane & 15;
    const int gate = lane >> 4;
    const float gscale = (gate == 2) ? -2.0f : -1.0f;  // tanh via 2*sigmoid(2x)-1
    const bool is_tanh = (gate == 2);

    // W_hh row for this lane's gate element
    float wh[16];
    {
      const float* wr = W_hh + lane * HH;
#pragma unroll
      for (int kk = 0; kk < 16; kk++) wh[kk] = wr[kk];
    }

    float c = 0.0f;
    float hu[16];
#pragma unroll
    for (int kk = 0; kk < 16; kk++) hu[kk] = 0.0f;

    float g = xgs[lane];  // t=0 preactivation
    for (int tstep = 0; tstep < TT; tstep++) {
      // Prefetch next step's preactivation early (hidden under the chain)
      float gnext = xgs[((tstep + 1) & 127) * GG + lane];

      // g += h . W_hh[j,:]  -- 4 split accumulators to shorten the dep chain
      float a0 = fmaf(hu[0], wh[0], g);
      a0 = fmaf(hu[1], wh[1], a0);
      a0 = fmaf(hu[2], wh[2], a0);
      a0 = fmaf(hu[3], wh[3], a0);
      float a1 = hu[4] * wh[4];
      a1 = fmaf(hu[5], wh[5], a1);
      a1 = fmaf(hu[6], wh[6], a1);
      a1 = fmaf(hu[7], wh[7], a1);
      float a2 = hu[8] * wh[8];
      a2 = fmaf(hu[9], wh[9], a2);
      a2 = fmaf(hu[10], wh[10], a2);
      a2 = fmaf(hu[11], wh[11], a2);
      float a3 = hu[12] * wh[12];
      a3 = fmaf(hu[13], wh[13], a3);
      a3 = fmaf(hu[14], wh[14], a3);
      a3 = fmaf(hu[15], wh[15], a3);
      float gv_ = (a0 + a1) + (a2 + a3);

      // Branchless sigmoid/tanh: e = exp(gscale*g); s = 1/(1+e)
      float e = __expf(gv_ * gscale);
      float s = __builtin_amdgcn_rcpf(1.0f + e);
      float act = is_tanh ? (2.0f * s - 1.0f) : s;

      // Gate exchange (ds_bpermute): lane gets i,f,g,o for its k
      float iv = __shfl(act, k);
      float fv = __shfl(act, k + 16);
      float gg = __shfl(act, k + 32);
      float ov = __shfl(act, k + 48);

      c = fmaf(fv, c, iv * gg);
      // tanh(c) = 2/(1+exp(-2c)) - 1
      float e2 = __expf(-2.0f * c);
      float tc = fmaf(2.0f, __builtin_amdgcn_rcpf(1.0f + e2), -1.0f);
      float hnew = ov * tc;

      if (lane < 16) hs[tstep][lane] = hnew;

      // Broadcast h (lanes 0..15 hold h_k for k=lane) as wave-uniform scalars
#pragma unroll
      for (int kk = 0; kk < 16; kk++)
        hu[kk] = __uint_as_float(__builtin_amdgcn_readlane(__float_as_uint(hnew), kk));

      g = gnext;
    }
  }
  __syncthreads();

  // Output projection: out[b, t, cc] = hs[t] . W_out[cc,:] + b_out[cc]
  float* outb = out + (size_t)b * TT * CC;
  for (int idx = t; idx < TT * CC; idx += 256) {
    int tt = idx / CC;
    int cc = idx - tt * CC;
    const float* wr = W_out + cc * HH;
    float accv = b_out[cc];
#pragma unroll
    for (int kk = 0; kk < 16; kk++) accv = fmaf(hs[tt][kk], wr[kk], accv);
    outb[idx] = accv;
  }
}

// ---------------------------------------------------------------------------
extern "C" void kernel_launch(void* const* d_in, const int* in_sizes, int n_in,
                              void* d_out, int out_size, void* d_ws, size_t ws_size,
                              hipStream_t stream) {
  const int*   x     = (const int*)d_in[0];
  const float* emb   = (const float*)d_in[1];
  const float* W_ih  = (const float*)d_in[2];
  const float* W_hh  = (const float*)d_in[3];
  const float* b_ih  = (const float*)d_in[4];
  const float* b_hh  = (const float*)d_in[5];
  const float* W_out = (const float*)d_in[6];
  const float* b_out = (const float*)d_in[7];
  float* out = (float*)d_out;
  float* xg  = (float*)d_ws;  // [32768][64] fp32 = 8.4 MB scratch

  xg_gemm_kernel<<<ROWS / 64, 256, 0, stream>>>(x, emb, W_ih, b_ih, b_hh, xg);
  lstm_seq_kernel<<<BB, 256, 0, stream>>>(xg, W_hh, W_out, b_out, out);
}